// Round 1
// 248.859 us; speedup vs baseline: 1.0281x; 1.0281x over previous
//
#include <hip/hip_runtime.h>
#include <math.h>

// FeatureNormalizedMSE: NaN-omitted, feature-weighted, per-sample-normalized MSE.
// B=2048, F=16384. Memory-bound: 268 MB fp32 compulsory reads.
// R5 theory: rocprof top-5 shows only harness 512 MiB poison fills (~78 us @ 85%
// HBM peak); fnmse_partial is absent => < 78 us, i.e. >= 3.4 TB/s. Remaining
// controllable gap to the 43 us read roofline is attacked by (a) issuing all 12
// loads per thread up front (max MLP, one monotone vmcnt chain instead of the
// 2-stage rotate's per-stage drain), (b) removing atomicAdd + the 16 KB
// hipMemsetAsync dispatch: each block writes a unique ws slot (plain stores
// overwrite the 0xAA poison, no init needed), finalize reads coalesced float4.

#define B_SAMPLES 2048
#define F_FEATURES 16384
#define THREADS 256
#define CHUNKS 4
#define F_CHUNK (F_FEATURES / CHUNKS)          // 4096 floats = 1024 float4
#define V_PER_THREAD (F_CHUNK / 4 / THREADS)   // 4 float4 per thread per stream

typedef float fx4 __attribute__((ext_vector_type(4)));

__global__ __launch_bounds__(THREADS) void fnmse_partial(
    const float* __restrict__ output,
    const float* __restrict__ target,
    const float* __restrict__ fw,
    float* __restrict__ ws_sq,     // [B][CHUNKS] — unique slot per block, no atomics
    float* __restrict__ ws_ct)     // [B][CHUNKS]
{
    const int b = blockIdx.x >> 2;         // sample
    const int c = blockIdx.x & 3;          // chunk within sample
    const int tid = threadIdx.x;

    const fx4* __restrict__ o4 = (const fx4*)(output + (size_t)b * F_FEATURES + c * F_CHUNK);
    const fx4* __restrict__ t4 = (const fx4*)(target + (size_t)b * F_FEATURES + c * F_CHUNK);
    const fx4* __restrict__ w4 = (const fx4*)(fw + c * F_CHUNK);

    // Issue ALL loads up front: 8 nontemporal (streaming, no L2/L3 pollution so
    // fw stays cache-hot) + 4 cached fw loads = 12 x 16 B in flight per thread.
    fx4 o[V_PER_THREAD], t[V_PER_THREAD], w[V_PER_THREAD];
    #pragma unroll
    for (int k = 0; k < V_PER_THREAD; ++k) {
        const int v = k * THREADS + tid;   // coalesced: lane i -> base + i*16B
        o[k] = __builtin_nontemporal_load(o4 + v);
        t[k] = __builtin_nontemporal_load(t4 + v);
    }
    #pragma unroll
    for (int k = 0; k < V_PER_THREAD; ++k)
        w[k] = w4[k * THREADS + tid];      // fw is hot/small — normal cached load

    float sumsq = 0.0f;
    float cnt   = 0.0f;
    #pragma unroll
    for (int k = 0; k < V_PER_THREAD; ++k) {
        #pragma unroll
        for (int j = 0; j < 4; ++j) {
            const bool m = !isnan(t[k][j]);
            const float r = m ? (t[k][j] - o[k][j]) * w[k][j] : 0.0f;
            sumsq = fmaf(r, r, sumsq);
            cnt += m ? 1.0f : 0.0f;
        }
    }

    // wave64 butterfly reduce
    #pragma unroll
    for (int off = 32; off > 0; off >>= 1) {
        sumsq += __shfl_down(sumsq, off, 64);
        cnt   += __shfl_down(cnt,   off, 64);
    }

    __shared__ float s_sq[THREADS / 64];
    __shared__ float s_ct[THREADS / 64];
    const int wave = tid >> 6;
    const int lane = tid & 63;
    if (lane == 0) { s_sq[wave] = sumsq; s_ct[wave] = cnt; }
    __syncthreads();

    if (tid == 0) {
        // Plain store to a unique slot — overwrites 0xAA poison, no memset needed.
        ws_sq[b * CHUNKS + c] = s_sq[0] + s_sq[1] + s_sq[2] + s_sq[3];
        ws_ct[b * CHUNKS + c] = s_ct[0] + s_ct[1] + s_ct[2] + s_ct[3];
    }
}

// Pass 2: out[0] = sum_b (sum_c sq[b][c]) / (sum_c ct[b][c]). One block.
// Each sample's 4 chunk-partials are contiguous -> one coalesced float4 per stream.
__global__ __launch_bounds__(THREADS) void fnmse_finalize(
    const float* __restrict__ ws_sq,
    const float* __restrict__ ws_ct,
    float* __restrict__ out)
{
    const int tid = threadIdx.x;
    const fx4* __restrict__ sq4 = (const fx4*)ws_sq;   // [B] float4
    const fx4* __restrict__ ct4 = (const fx4*)ws_ct;   // [B] float4

    float acc = 0.0f;
    #pragma unroll
    for (int s = 0; s < B_SAMPLES / THREADS; ++s) {
        const int b = s * THREADS + tid;               // coalesced 16 B/lane
        const fx4 q = sq4[b];
        const fx4 n = ct4[b];
        acc += ((q[0] + q[1]) + (q[2] + q[3])) / ((n[0] + n[1]) + (n[2] + n[3]));
    }
    #pragma unroll
    for (int off = 32; off > 0; off >>= 1)
        acc += __shfl_down(acc, off, 64);

    __shared__ float s_a[THREADS / 64];
    const int wave = tid >> 6;
    const int lane = tid & 63;
    if (lane == 0) s_a[wave] = acc;
    __syncthreads();
    if (tid == 0) out[0] = s_a[0] + s_a[1] + s_a[2] + s_a[3];
}

extern "C" void kernel_launch(void* const* d_in, const int* in_sizes, int n_in,
                              void* d_out, int out_size, void* d_ws, size_t ws_size,
                              hipStream_t stream) {
    const float* output = (const float*)d_in[0];  // [B,C,H,W] fp32
    const float* target = (const float*)d_in[1];  // [B,C,H,W] fp32 with NaNs
    // d_in[2] = e_exp (unused), d_in[3] = sample_weight (unused)
    const float* fw     = (const float*)d_in[4];  // [F,1] fp32
    float* out = (float*)d_out;

    float* ws_sq = (float*)d_ws;                       // [B][CHUNKS] = 32 KB
    float* ws_ct = ws_sq + B_SAMPLES * CHUNKS;         // [B][CHUNKS] = 32 KB

    // No memset: every ws slot we read is unconditionally written by exactly
    // one block of fnmse_partial before fnmse_finalize runs (stream order).

    fnmse_partial<<<B_SAMPLES * CHUNKS, THREADS, 0, stream>>>(output, target, fw, ws_sq, ws_ct);
    fnmse_finalize<<<1, THREADS, 0, stream>>>(ws_sq, ws_ct, out);
}